// Round 6
// baseline (289.911 us; speedup 1.0000x reference)
//
#include <hip/hip_runtime.h>

typedef _Float16 h16;
typedef _Float16 half8 __attribute__((ext_vector_type(8)));
typedef _Float16 half4v __attribute__((ext_vector_type(4)));
typedef float floatx4 __attribute__((ext_vector_type(4)));

static constexpr int Bb_ = 4, S_ = 2048, D_ = 1024;

static __device__ __forceinline__ void gl_lds16(const void* g, void* l) {
  __builtin_amdgcn_global_load_lds(
      (const __attribute__((address_space(1))) unsigned int*)g,
      (__attribute__((address_space(3))) unsigned int*)l, 16, 0, 0);
}

// ---- fused prep: Qh = fp16(Q), Kh = fp16(Rq^T Rk Q), QhT = Qh transposed ----
// LDS transpose tile uses XOR swizzle (phys elem = e ^ 8*(row>>3)): transpose
// reads are 2-way (free), writes 4-way. (Round 4: ~11 us faster than pad-72.)
__global__ __launch_bounds__(256) void k_prep_t(const float* __restrict__ Q,
                                                const float* __restrict__ rot,
                                                h16* __restrict__ Qh,
                                                h16* __restrict__ Kh,
                                                h16* __restrict__ QhT) {
  __shared__ __align__(16) h16 tile[64][64];
  int d0 = blockIdx.x * 64, s0 = blockIdx.y * 64, b = blockIdx.z;
  int t = threadIdx.x;
  const float* Qb = Q + ((size_t)b * S_ + s0) * D_ + d0;
  h16* Qhb = Qh + ((size_t)b * S_ + s0) * D_ + d0;
  h16* Khb = Kh + ((size_t)b * S_ + s0) * D_ + d0;
#pragma unroll
  for (int i = 0; i < 4; ++i) {
    int c = t + 256 * i;     // 0..1023 float4 chunks of the 64x64 tile
    int row = c >> 4;        // s-local
    int col = (c & 15) * 4;  // d-local
    float4 q = *(const float4*)&Qb[(size_t)row * D_ + col];
    int dg = (d0 + col) >> 2;
    float4 r0 = ((const float4*)rot)[dg];           // rot row 0 (q)
    float4 r1 = ((const float4*)rot)[D_ / 4 + dg];  // rot row 1 (k)
    float inq0 = rsqrtf(r0.x * r0.x + r0.y * r0.y);
    float ink0 = rsqrtf(r1.x * r1.x + r1.y * r1.y);
    float cc0 = (r0.x * r1.x + r0.y * r1.y) * inq0 * ink0;
    float ss0 = (r0.x * r1.y - r0.y * r1.x) * inq0 * ink0;
    float y0 = cc0 * q.x - ss0 * q.y;
    float y1 = cc0 * q.y + ss0 * q.x;
    float inq1 = rsqrtf(r0.z * r0.z + r0.w * r0.w);
    float ink1 = rsqrtf(r1.z * r1.z + r1.w * r1.w);
    float cc1 = (r0.z * r1.z + r0.w * r1.w) * inq1 * ink1;
    float ss1 = (r0.z * r1.w - r0.w * r1.z) * inq1 * ink1;
    float y2 = cc1 * q.z - ss1 * q.w;
    float y3 = cc1 * q.w + ss1 * q.z;
    half4v kh = {(h16)y0, (h16)y1, (h16)y2, (h16)y3};
    half4v qh = {(h16)q.x, (h16)q.y, (h16)q.z, (h16)q.w};
    *(half4v*)&Qhb[(size_t)row * D_ + col] = qh;
    *(half4v*)&Khb[(size_t)row * D_ + col] = kh;
    int pcol = col ^ ((row >> 3) << 3);  // XOR swizzle, keeps 8B alignment
    *(half4v*)&tile[row][pcol] = qh;
  }
  __syncthreads();
  h16* dst = QhT + ((size_t)b * D_ + d0) * S_ + s0;
#pragma unroll
  for (int i = 0; i < 2; ++i) {
    int c = t + 256 * i;   // 0..511 half8 chunks of the transposed tile
    int drow = c >> 3;     // d-local
    int sc = (c & 7) * 8;  // s-local, multiple of 8
    int xr = sc;           // (sc+j)>>3<<3 == sc for j<8
    half8 v;
#pragma unroll
    for (int j = 0; j < 8; ++j) v[j] = tile[sc + j][drow ^ xr];
    *(half8*)&dst[(size_t)drow * S_ + sc] = v;
  }
}

// ---------------- GEMM  C[m][n] = sum_k A[m][k] * Bt[n][k]  (fp16 in, fp32 out)
// 128x128 tile, BK=64, 4 waves each 64x64 (4x4 frags of 16x16x32).
// A: global_load_lds staging, XOR-swizzled (0 conflicts, R2) — LDS-resident.
// B: DIRECT global->register fragments, double-buffered at half-slab (BK=32)
// granularity. Prefetch placement is the whole point (R4 failed without it):
//   bnxt (half 1) issues at top of half-0 compute  -> no barrier before use.
//   bcur (next slab) issues at top of half-1 compute -> covered by half-1
//   compute when the end-of-iter barrier drains vmcnt.
// This halves LDS-unit traffic (96->48 KB/iter), the measured binding pipe.
__global__ __launch_bounds__(256) void k_gemm_bt(
    const char* __restrict__ A, int a_pitch, unsigned long long a_batch,
    const char* __restrict__ Bt, int b_pitch, unsigned long long b_batch,
    float* __restrict__ C, int c_pitch, unsigned long long c_batch, int Kdim) {
  __shared__ __align__(16) h16 As[2][128 * 32];
  const int t = threadIdx.x;
  const int lane = t & 63;
  const int w = t >> 6;
  const int wm = (w >> 1) * 64;
  const int wn = (w & 1) * 64;
  const char* Ab = A + (unsigned long long)blockIdx.z * a_batch +
                   (unsigned long long)blockIdx.y * 128ull * (unsigned long long)a_pitch;
  const char* Bbp = Bt + (unsigned long long)blockIdx.z * b_batch +
                    (unsigned long long)blockIdx.x * 128ull * (unsigned long long)b_pitch;
  const int o0 = t * 16;  // physical LDS byte offset (wave-uniform base + lane*16)
  const int o1 = o0 + 4096;
  const int ar0 = o0 >> 6, ar1 = o1 >> 6;
  const int ac0 = ((((o0 >> 4) & 3) ^ ((ar0 >> 1) & 3)) << 4);
  const int ac1 = ((((o1 >> 4) & 3) ^ ((ar1 >> 1) & 3)) << 4);
  const int mrow = lane & 15;
  const int kc = lane >> 4;                          // logical k-chunk 0..3
  const int koff = ((kc ^ ((mrow >> 1) & 3)) << 3);  // swizzled element offset
  // B fragment lane base: row = wn + mrow (+j*16), k-chunk = kc*16B
  const char* Blp = Bbp + (unsigned long long)(wn + mrow) * (unsigned long long)b_pitch +
                    (kc << 4);
  const size_t jstride = (size_t)16 * (size_t)b_pitch;

  floatx4 acc[4][4];
#pragma unroll
  for (int i = 0; i < 4; ++i)
#pragma unroll
    for (int j = 0; j < 4; ++j) acc[i][j] = (floatx4){0.f, 0.f, 0.f, 0.f};

  half8 bcur[4], bnxt[4];
#pragma unroll
  for (int j = 0; j < 4; ++j) bcur[j] = *(const half8*)(Blp + (size_t)j * jstride);

  for (int kt = 0; kt < Kdim; kt += 64) {
    const int kb = kt * 2;  // byte col of this 64-K slab
    gl_lds16(Ab + (unsigned long long)ar0 * a_pitch + kb + ac0, (char*)As[0] + o0);
    gl_lds16(Ab + (unsigned long long)ar1 * a_pitch + kb + ac1, (char*)As[0] + o1);
    gl_lds16(Ab + (unsigned long long)ar0 * a_pitch + kb + 64 + ac0, (char*)As[1] + o0);
    gl_lds16(Ab + (unsigned long long)ar1 * a_pitch + kb + 64 + ac1, (char*)As[1] + o1);
    __syncthreads();
    // ---- half 0: prefetch bnxt (this slab, half 1), compute with bcur ----
#pragma unroll
    for (int j = 0; j < 4; ++j)
      bnxt[j] = *(const half8*)(Blp + (size_t)j * jstride + kb + 64);
    {
      half8 a[4];
#pragma unroll
      for (int i = 0; i < 4; ++i)
        a[i] = *(const half8*)&As[0][(wm + i * 16 + mrow) * 32 + koff];
#pragma unroll
      for (int i = 0; i < 4; ++i)
#pragma unroll
        for (int j = 0; j < 4; ++j)
          acc[i][j] = __builtin_amdgcn_mfma_f32_16x16x32_f16(a[i], bcur[j], acc[i][j], 0, 0, 0);
    }
    // ---- half 1: prefetch bcur (next slab, half 0), compute with bnxt ----
    if (kt + 64 < Kdim) {
#pragma unroll
      for (int j = 0; j < 4; ++j)
        bcur[j] = *(const half8*)(Blp + (size_t)j * jstride + kb + 128);
    }
    {
      half8 a[4];
#pragma unroll
      for (int i = 0; i < 4; ++i)
        a[i] = *(const half8*)&As[1][(wm + i * 16 + mrow) * 32 + koff];
#pragma unroll
      for (int i = 0; i < 4; ++i)
#pragma unroll
        for (int j = 0; j < 4; ++j)
          acc[i][j] = __builtin_amdgcn_mfma_f32_16x16x32_f16(a[i], bnxt[j], acc[i][j], 0, 0, 0);
    }
    __syncthreads();
  }

  float* Cb = C + (unsigned long long)blockIdx.z * c_batch;
  const int m0 = blockIdx.y * 128 + wm;
  const int n0 = blockIdx.x * 128 + wn;
  const int col = lane & 15;
  const int rquad = (lane >> 4) * 4;  // C/D: col=lane&15, row=(lane>>4)*4+reg
#pragma unroll
  for (int i = 0; i < 4; ++i)
#pragma unroll
    for (int j = 0; j < 4; ++j)
#pragma unroll
      for (int r = 0; r < 4; ++r)
        Cb[(unsigned long long)(m0 + i * 16 + rquad + r) * c_pitch + (n0 + j * 16 + col)] =
            acc[i][j][r];
}

// ---- softmax: one WAVE per row (4 rows/block, no barriers) ----
__global__ __launch_bounds__(256) void k_softmax(float* __restrict__ Sl,
                                                 float* __restrict__ lrow,
                                                 const float* __restrict__ scale_p) {
  int wv = threadIdx.x >> 6, ln = threadIdx.x & 63;
  int row = blockIdx.x * 4 + wv;  // 0..B*S-1
  float* base = Sl + (size_t)row * S_;
  float4 c[8];
#pragma unroll
  for (int r = 0; r < 4; ++r) {  // lane reads 32B contiguous per step, 8 deep
    c[2 * r] = ((const float4*)base)[2 * ln + 128 * r];
    c[2 * r + 1] = ((const float4*)base)[2 * ln + 1 + 128 * r];
  }
  float m = -1e30f;
#pragma unroll
  for (int r = 0; r < 8; ++r)
    m = fmaxf(m, fmaxf(fmaxf(c[r].x, c[r].y), fmaxf(c[r].z, c[r].w)));
#pragma unroll
  for (int off = 32; off; off >>= 1) m = fmaxf(m, __shfl_xor(m, off));
  float alpha = 2.0f / scale_p[0];  // +2, bias, 1/l all cancel under normalize
  h16* prow = (h16*)base;
  float s = 0.f;
#pragma unroll
  for (int r = 0; r < 4; ++r) {
    float p0 = __expf((c[2 * r].x - m) * alpha);
    float p1 = __expf((c[2 * r].y - m) * alpha);
    float p2 = __expf((c[2 * r].z - m) * alpha);
    float p3 = __expf((c[2 * r].w - m) * alpha);
    float p4 = __expf((c[2 * r + 1].x - m) * alpha);
    float p5 = __expf((c[2 * r + 1].y - m) * alpha);
    float p6 = __expf((c[2 * r + 1].z - m) * alpha);
    float p7 = __expf((c[2 * r + 1].w - m) * alpha);
    s += ((p0 + p1) + (p2 + p3)) + ((p4 + p5) + (p6 + p7));
    half8 pv = {(h16)p0, (h16)p1, (h16)p2, (h16)p3,
                (h16)p4, (h16)p5, (h16)p6, (h16)p7};
    *(half8*)&prow[8 * ln + 512 * r] = pv;  // 16B/lane coalesced
  }
#pragma unroll
  for (int off = 32; off; off >>= 1) s += __shfl_xor(s, off);
  if (ln == 0) lrow[row] = s;
}

// ---- epilogue: one WAVE per row (4 rows/block, no barriers) ----
__global__ __launch_bounds__(256) void k_epilogue(float* __restrict__ O,
                                                  const float* __restrict__ lrow,
                                                  const float* __restrict__ rot) {
  int wv = threadIdx.x >> 6, ln = threadIdx.x & 63;
  int row = blockIdx.x * 4 + wv;
  float* base = O + (size_t)row * D_;
  float4 u[4];
#pragma unroll
  for (int r = 0; r < 4; ++r) u[r] = ((const float4*)base)[ln + 64 * r];
  float ss = 0.f;
#pragma unroll
  for (int r = 0; r < 4; ++r)
    ss += u[r].x * u[r].x + u[r].y * u[r].y + u[r].z * u[r].z + u[r].w * u[r].w;
#pragma unroll
  for (int off = 32; off; off >>= 1) ss += __shfl_xor(ss, off);
  float l = lrow[row];
  float inner = ss / (l * l);
  float denom = sqrtf(fmaxf(inner, 1e-8f));
  float f = 1.0f / (l * denom);
#pragma unroll
  for (int r = 0; r < 4; ++r) {
    float4 r2 = ((const float4*)rot)[2 * (D_ / 4) + ln + 64 * r];  // rot row 2 (v)
    float z0 = u[r].x * f, z1 = u[r].y * f, z2 = u[r].z * f, z3 = u[r].w * f;
    float in0 = rsqrtf(r2.x * r2.x + r2.y * r2.y);
    float cv0 = r2.x * in0, sv0 = r2.y * in0;
    float in1 = rsqrtf(r2.z * r2.z + r2.w * r2.w);
    float cv1 = r2.z * in1, sv1 = r2.w * in1;
    float4 o;
    o.x = cv0 * z0 - sv0 * z1;
    o.y = cv0 * z1 + sv0 * z0;
    o.z = cv1 * z2 - sv1 * z3;
    o.w = cv1 * z3 + sv1 * z2;
    ((float4*)base)[ln + 64 * r] = o;
  }
}

extern "C" void kernel_launch(void* const* d_in, const int* in_sizes, int n_in,
                              void* d_out, int out_size, void* d_ws, size_t ws_size,
                              hipStream_t stream) {
  const float* Q = (const float*)d_in[0];
  const float* rot = (const float*)d_in[1];
  const float* scale = (const float*)d_in[2];
  // bias (d_in[3]) is a scalar added to all logits -> cancels in softmax exactly.
  float* O = (float*)d_out;
  char* ws = (char*)d_ws;
  const size_t MB = 1024ull * 1024ull;
  h16* Qh = (h16*)(ws);                   // 16 MB  [B][S][D]
  h16* Kh = (h16*)(ws + 16 * MB);         // 16 MB  [B][S][D]  combined-rotated
  h16* QhT = (h16*)(ws + 32 * MB);        // 16 MB  [B][D][S]
  float* Sl = (float*)(ws + 48 * MB);     // 64 MB  [B][S][S] logits fp32 / P fp16 pitched
  float* lrow = (float*)(ws + 112 * MB);  // 32 KB  [B*S]
  // total ws needed: ~117.5 MB

  k_prep_t<<<dim3(D_ / 64, S_ / 64, Bb_), 256, 0, stream>>>(Q, rot, Qh, Kh, QhT);
  // GEMM1: logits[m][n] = Qh[m] . Kh[n]   (M=N=2048, K=1024)
  k_gemm_bt<<<dim3(S_ / 128, S_ / 128, Bb_), 256, 0, stream>>>(
      (const char*)Qh, D_ * 2, (unsigned long long)S_ * D_ * 2,
      (const char*)Kh, D_ * 2, (unsigned long long)S_ * D_ * 2,
      Sl, S_, (unsigned long long)S_ * S_, D_);
  k_softmax<<<dim3(Bb_ * S_ / 4), 256, 0, stream>>>(Sl, lrow, scale);
  // GEMM2: U[m][d] = P[m] . QhT[d]        (M=2048, N=1024, K=2048)
  k_gemm_bt<<<dim3(D_ / 128, S_ / 128, Bb_), 256, 0, stream>>>(
      (const char*)Sl, S_ * 4, (unsigned long long)S_ * S_ * 4,
      (const char*)QhT, S_ * 2, (unsigned long long)D_ * S_ * 2,
      O, D_, (unsigned long long)S_ * D_, S_);
  k_epilogue<<<dim3(Bb_ * S_ / 4), 256, 0, stream>>>(O, lrow, rot);
}

// Round 7
// 216.383 us; speedup vs baseline: 1.3398x; 1.3398x over previous
//
#include <hip/hip_runtime.h>

typedef _Float16 h16;
typedef _Float16 half8 __attribute__((ext_vector_type(8)));
typedef _Float16 half4v __attribute__((ext_vector_type(4)));
typedef float floatx4 __attribute__((ext_vector_type(4)));

static constexpr int Bb_ = 4, S_ = 2048, D_ = 1024;

static __device__ __forceinline__ void gl_lds16(const void* g, void* l) {
  __builtin_amdgcn_global_load_lds(
      (const __attribute__((address_space(1))) unsigned int*)g,
      (__attribute__((address_space(3))) unsigned int*)l, 16, 0, 0);
}

// ---- fused prep: Qh = fp16(Q), Kh = fp16(Rq^T Rk Q), QhT = Qh transposed ----
// LDS transpose tile uses XOR swizzle (phys elem = e ^ 8*(row>>3)): transpose
// reads are 2-way (free), writes 4-way. (Round 4: ~11 us faster than pad-72.)
__global__ __launch_bounds__(256) void k_prep_t(const float* __restrict__ Q,
                                                const float* __restrict__ rot,
                                                h16* __restrict__ Qh,
                                                h16* __restrict__ Kh,
                                                h16* __restrict__ QhT) {
  __shared__ __align__(16) h16 tile[64][64];
  int d0 = blockIdx.x * 64, s0 = blockIdx.y * 64, b = blockIdx.z;
  int t = threadIdx.x;
  const float* Qb = Q + ((size_t)b * S_ + s0) * D_ + d0;
  h16* Qhb = Qh + ((size_t)b * S_ + s0) * D_ + d0;
  h16* Khb = Kh + ((size_t)b * S_ + s0) * D_ + d0;
#pragma unroll
  for (int i = 0; i < 4; ++i) {
    int c = t + 256 * i;     // 0..1023 float4 chunks of the 64x64 tile
    int row = c >> 4;        // s-local
    int col = (c & 15) * 4;  // d-local
    float4 q = *(const float4*)&Qb[(size_t)row * D_ + col];
    int dg = (d0 + col) >> 2;
    float4 r0 = ((const float4*)rot)[dg];           // rot row 0 (q)
    float4 r1 = ((const float4*)rot)[D_ / 4 + dg];  // rot row 1 (k)
    float inq0 = rsqrtf(r0.x * r0.x + r0.y * r0.y);
    float ink0 = rsqrtf(r1.x * r1.x + r1.y * r1.y);
    float cc0 = (r0.x * r1.x + r0.y * r1.y) * inq0 * ink0;
    float ss0 = (r0.x * r1.y - r0.y * r1.x) * inq0 * ink0;
    float y0 = cc0 * q.x - ss0 * q.y;
    float y1 = cc0 * q.y + ss0 * q.x;
    float inq1 = rsqrtf(r0.z * r0.z + r0.w * r0.w);
    float ink1 = rsqrtf(r1.z * r1.z + r1.w * r1.w);
    float cc1 = (r0.z * r1.z + r0.w * r1.w) * inq1 * ink1;
    float ss1 = (r0.z * r1.w - r0.w * r1.z) * inq1 * ink1;
    float y2 = cc1 * q.z - ss1 * q.w;
    float y3 = cc1 * q.w + ss1 * q.z;
    half4v kh = {(h16)y0, (h16)y1, (h16)y2, (h16)y3};
    half4v qh = {(h16)q.x, (h16)q.y, (h16)q.z, (h16)q.w};
    *(half4v*)&Qhb[(size_t)row * D_ + col] = qh;
    *(half4v*)&Khb[(size_t)row * D_ + col] = kh;
    int pcol = col ^ ((row >> 3) << 3);  // XOR swizzle, keeps 8B alignment
    *(half4v*)&tile[row][pcol] = qh;
  }
  __syncthreads();
  h16* dst = QhT + ((size_t)b * D_ + d0) * S_ + s0;
#pragma unroll
  for (int i = 0; i < 2; ++i) {
    int c = t + 256 * i;   // 0..511 half8 chunks of the transposed tile
    int drow = c >> 3;     // d-local
    int sc = (c & 7) * 8;  // s-local, multiple of 8
    int xr = sc;           // (sc+j)>>3<<3 == sc for j<8
    half8 v;
#pragma unroll
    for (int j = 0; j < 8; ++j) v[j] = tile[sc + j][drow ^ xr];
    *(half8*)&dst[(size_t)drow * S_ + sc] = v;
  }
}

// ---------------- GEMM  C[m][n] = sum_k A[m][k] * Bt[n][k]  (fp16 in)
// Proven R5 structure: 128x128 tile, BK=64 as two BK=32 half-buffers (one
// barrier pair per 64-K), 4 waves each 64x64 (4x4 frags of 16x16x32),
// XOR-swizzled LDS chunks (measured 0 bank conflicts).
// NOTE (R4+R6): B must stay in LDS. Register B-fragments from global — with
// or without prefetch-under-compute — collapse to MfmaUtil 13% because the
// pre-barrier vmcnt(0) drain exposes their latency. Do not retry.
// OUT16: write C as fp16 (GEMM1 logits) vs fp32 (GEMM2 output).
template <bool OUT16>
__global__ __launch_bounds__(256) void k_gemm_bt(
    const char* __restrict__ A, int a_pitch, unsigned long long a_batch,
    const char* __restrict__ Bt, int b_pitch, unsigned long long b_batch,
    void* __restrict__ C, int c_pitch, unsigned long long c_batch, int Kdim) {
  __shared__ __align__(16) h16 As[2][128 * 32];
  __shared__ __align__(16) h16 Bs[2][128 * 32];
  const int t = threadIdx.x;
  const int lane = t & 63;
  const int w = t >> 6;
  const int wm = (w >> 1) * 64;
  const int wn = (w & 1) * 64;
  const char* Ab = A + (unsigned long long)blockIdx.z * a_batch +
                   (unsigned long long)blockIdx.y * 128ull * (unsigned long long)a_pitch;
  const char* Bbp = Bt + (unsigned long long)blockIdx.z * b_batch +
                    (unsigned long long)blockIdx.x * 128ull * (unsigned long long)b_pitch;
  const int o0 = t * 16;  // physical LDS byte offset (wave-uniform base + lane*16)
  const int o1 = o0 + 4096;
  const int ar0 = o0 >> 6, ar1 = o1 >> 6;
  const int ac0 = ((((o0 >> 4) & 3) ^ ((ar0 >> 1) & 3)) << 4);
  const int ac1 = ((((o1 >> 4) & 3) ^ ((ar1 >> 1) & 3)) << 4);
  const int mrow = lane & 15;
  const int kc = lane >> 4;                          // logical k-chunk 0..3
  const int koff = ((kc ^ ((mrow >> 1) & 3)) << 3);  // swizzled element offset

  floatx4 acc[4][4];
#pragma unroll
  for (int i = 0; i < 4; ++i)
#pragma unroll
    for (int j = 0; j < 4; ++j) acc[i][j] = (floatx4){0.f, 0.f, 0.f, 0.f};

  for (int kt = 0; kt < Kdim; kt += 64) {
    const int kb = kt * 2;  // byte col of this 64-K slab; halves at +0 / +64 B
#pragma unroll
    for (int h = 0; h < 2; ++h) {
      const int hb = kb + h * 64;
      gl_lds16(Ab + (unsigned long long)ar0 * a_pitch + hb + ac0, (char*)As[h] + o0);
      gl_lds16(Ab + (unsigned long long)ar1 * a_pitch + hb + ac1, (char*)As[h] + o1);
      gl_lds16(Bbp + (unsigned long long)ar0 * b_pitch + hb + ac0, (char*)Bs[h] + o0);
      gl_lds16(Bbp + (unsigned long long)ar1 * b_pitch + hb + ac1, (char*)Bs[h] + o1);
    }
    __syncthreads();
#pragma unroll
    for (int h = 0; h < 2; ++h) {
      half8 a[4], b[4];
#pragma unroll
      for (int i = 0; i < 4; ++i)
        a[i] = *(const half8*)&As[h][(wm + i * 16 + mrow) * 32 + koff];
#pragma unroll
      for (int i = 0; i < 4; ++i)
        b[i] = *(const half8*)&Bs[h][(wn + i * 16 + mrow) * 32 + koff];
#pragma unroll
      for (int i = 0; i < 4; ++i)
#pragma unroll
        for (int j = 0; j < 4; ++j)
          acc[i][j] = __builtin_amdgcn_mfma_f32_16x16x32_f16(a[i], b[j], acc[i][j], 0, 0, 0);
    }
    __syncthreads();
  }

  const int m0 = blockIdx.y * 128 + wm;
  const int n0 = blockIdx.x * 128 + wn;
  const int col = lane & 15;
  const int rquad = (lane >> 4) * 4;  // C/D: col=lane&15, row=(lane>>4)*4+reg
  if constexpr (OUT16) {
    h16* Cb = (h16*)C + (unsigned long long)blockIdx.z * c_batch;
#pragma unroll
    for (int i = 0; i < 4; ++i)
#pragma unroll
      for (int j = 0; j < 4; ++j)
#pragma unroll
        for (int r = 0; r < 4; ++r)
          Cb[(unsigned long long)(m0 + i * 16 + rquad + r) * c_pitch + (n0 + j * 16 + col)] =
              (h16)acc[i][j][r];
  } else {
    float* Cb = (float*)C + (unsigned long long)blockIdx.z * c_batch;
#pragma unroll
    for (int i = 0; i < 4; ++i)
#pragma unroll
      for (int j = 0; j < 4; ++j)
#pragma unroll
        for (int r = 0; r < 4; ++r)
          Cb[(unsigned long long)(m0 + i * 16 + rquad + r) * c_pitch + (n0 + j * 16 + col)] =
              acc[i][j][r];
  }
}

// ---- softmax: one WAVE per row (4 rows/block, no barriers), fp16 in place --
// Reads fp16 logits, writes unnormalized exp(l - rowmax) as fp16 at the same
// addresses. No sum needed: the softmax denominator cancels exactly in the
// final normalize (out = U/||U||). Safety: the cross-lane max reduction makes
// every store depend on every lane's loads.
__global__ __launch_bounds__(256) void k_softmax(h16* __restrict__ Sl,
                                                 const float* __restrict__ scale_p) {
  int wv = threadIdx.x >> 6, ln = threadIdx.x & 63;
  int row = blockIdx.x * 4 + wv;  // 0..B*S-1
  h16* base = Sl + (size_t)row * S_;
  half8 c[4];
#pragma unroll
  for (int r = 0; r < 4; ++r) c[r] = ((const half8*)base)[ln + 64 * r];
  float m = -1e30f;
#pragma unroll
  for (int r = 0; r < 4; ++r)
#pragma unroll
    for (int j = 0; j < 8; ++j) m = fmaxf(m, (float)c[r][j]);
#pragma unroll
  for (int off = 32; off; off >>= 1) m = fmaxf(m, __shfl_xor(m, off));
  float alpha = 2.0f / scale_p[0];  // +2, bias, 1/sum all cancel under normalize
#pragma unroll
  for (int r = 0; r < 4; ++r) {
    half8 pv;
#pragma unroll
    for (int j = 0; j < 8; ++j) pv[j] = (h16)__expf(((float)c[r][j] - m) * alpha);
    ((half8*)base)[ln + 64 * r] = pv;  // 16B/lane coalesced, in place
  }
}

// ---- epilogue: one WAVE per row (4 rows/block, no barriers) ----
// out = (U/||U||) rotated by Rv. (Softmax denom cancels; reference clip can't
// trigger: ||ave|| >= ~0.02 >> 1e-4.)
__global__ __launch_bounds__(256) void k_epilogue(float* __restrict__ O,
                                                  const float* __restrict__ rot) {
  int wv = threadIdx.x >> 6, ln = threadIdx.x & 63;
  int row = blockIdx.x * 4 + wv;
  float* base = O + (size_t)row * D_;
  float4 u[4];
#pragma unroll
  for (int r = 0; r < 4; ++r) u[r] = ((const float4*)base)[ln + 64 * r];
  float ss = 0.f;
#pragma unroll
  for (int r = 0; r < 4; ++r)
    ss += u[r].x * u[r].x + u[r].y * u[r].y + u[r].z * u[r].z + u[r].w * u[r].w;
#pragma unroll
  for (int off = 32; off; off >>= 1) ss += __shfl_xor(ss, off);
  float f = rsqrtf(fmaxf(ss, 1e-30f));
#pragma unroll
  for (int r = 0; r < 4; ++r) {
    float4 r2 = ((const float4*)rot)[2 * (D_ / 4) + ln + 64 * r];  // rot row 2 (v)
    float z0 = u[r].x * f, z1 = u[r].y * f, z2 = u[r].z * f, z3 = u[r].w * f;
    float in0 = rsqrtf(r2.x * r2.x + r2.y * r2.y);
    float cv0 = r2.x * in0, sv0 = r2.y * in0;
    float in1 = rsqrtf(r2.z * r2.z + r2.w * r2.w);
    float cv1 = r2.z * in1, sv1 = r2.w * in1;
    float4 o;
    o.x = cv0 * z0 - sv0 * z1;
    o.y = cv0 * z1 + sv0 * z0;
    o.z = cv1 * z2 - sv1 * z3;
    o.w = cv1 * z3 + sv1 * z2;
    ((float4*)base)[ln + 64 * r] = o;
  }
}

extern "C" void kernel_launch(void* const* d_in, const int* in_sizes, int n_in,
                              void* d_out, int out_size, void* d_ws, size_t ws_size,
                              hipStream_t stream) {
  const float* Q = (const float*)d_in[0];
  const float* rot = (const float*)d_in[1];
  const float* scale = (const float*)d_in[2];
  // bias (d_in[3]) is a scalar added to all logits -> cancels in softmax exactly.
  float* O = (float*)d_out;
  char* ws = (char*)d_ws;
  const size_t MB = 1024ull * 1024ull;
  h16* Qh = (h16*)(ws);             // 16 MB  [B][S][D]
  h16* Kh = (h16*)(ws + 16 * MB);   // 16 MB  [B][S][D]  combined-rotated
  h16* QhT = (h16*)(ws + 32 * MB);  // 16 MB  [B][D][S]
  h16* Sl = (h16*)(ws + 48 * MB);   // 32 MB  [B][S][S] fp16 logits, then P in place
  // total ws needed: 80 MB

  k_prep_t<<<dim3(D_ / 64, S_ / 64, Bb_), 256, 0, stream>>>(Q, rot, Qh, Kh, QhT);
  // GEMM1: logits[m][n] = Qh[m] . Kh[n]   (M=N=2048, K=1024), fp16 out
  k_gemm_bt<true><<<dim3(S_ / 128, S_ / 128, Bb_), 256, 0, stream>>>(
      (const char*)Qh, D_ * 2, (unsigned long long)S_ * D_ * 2,
      (const char*)Kh, D_ * 2, (unsigned long long)S_ * D_ * 2,
      (void*)Sl, S_, (unsigned long long)S_ * S_, D_);
  k_softmax<<<dim3(Bb_ * S_ / 4), 256, 0, stream>>>(Sl, scale);
  // GEMM2: U[m][d] = P[m] . QhT[d]        (M=2048, N=1024, K=2048), fp32 out
  k_gemm_bt<false><<<dim3(D_ / 128, S_ / 128, Bb_), 256, 0, stream>>>(
      (const char*)Sl, S_ * 2, (unsigned long long)S_ * S_ * 2,
      (const char*)QhT, S_ * 2, (unsigned long long)D_ * S_ * 2,
      (void*)O, D_, (unsigned long long)S_ * D_, S_);
  k_epilogue<<<dim3(Bb_ * S_ / 4), 256, 0, stream>>>(O, rot);
}

// Round 8
// 208.682 us; speedup vs baseline: 1.3892x; 1.0369x over previous
//
#include <hip/hip_runtime.h>

typedef _Float16 h16;
typedef _Float16 half8 __attribute__((ext_vector_type(8)));
typedef _Float16 half4v __attribute__((ext_vector_type(4)));
typedef float floatx4 __attribute__((ext_vector_type(4)));

static constexpr int Bb_ = 4, S_ = 2048, D_ = 1024;

static __device__ __forceinline__ void gl_lds16(const void* g, void* l) {
  __builtin_amdgcn_global_load_lds(
      (const __attribute__((address_space(1))) unsigned int*)g,
      (__attribute__((address_space(3))) unsigned int*)l, 16, 0, 0);
}

// ---- fused prep: Qh = fp16(Q), Kh = fp16(Rq^T Rk Q), VhT = (Rv Q)^T fp16 ----
// Rv is folded here (ave.Rv = P.(Rv Q) by linearity) so the epilogue is a pure
// normalize. LDS transpose tile uses XOR swizzle (phys elem = e ^ 8*(row>>3)):
// transpose reads 2-way (free), writes 4-way. (R4: ~11 us faster than pad-72.)
__global__ __launch_bounds__(256) void k_prep_t(const float* __restrict__ Q,
                                                const float* __restrict__ rot,
                                                h16* __restrict__ Qh,
                                                h16* __restrict__ Kh,
                                                h16* __restrict__ VhT) {
  __shared__ __align__(16) h16 tile[64][64];
  int d0 = blockIdx.x * 64, s0 = blockIdx.y * 64, b = blockIdx.z;
  int t = threadIdx.x;
  const float* Qb = Q + ((size_t)b * S_ + s0) * D_ + d0;
  h16* Qhb = Qh + ((size_t)b * S_ + s0) * D_ + d0;
  h16* Khb = Kh + ((size_t)b * S_ + s0) * D_ + d0;
#pragma unroll
  for (int i = 0; i < 4; ++i) {
    int c = t + 256 * i;     // 0..1023 float4 chunks of the 64x64 tile
    int row = c >> 4;        // s-local
    int col = (c & 15) * 4;  // d-local
    float4 q = *(const float4*)&Qb[(size_t)row * D_ + col];
    int dg = (d0 + col) >> 2;
    float4 r0 = ((const float4*)rot)[dg];               // rot row 0 (q)
    float4 r1 = ((const float4*)rot)[D_ / 4 + dg];      // rot row 1 (k)
    float4 r2 = ((const float4*)rot)[2 * D_ / 4 + dg];  // rot row 2 (v)
    // combined rotation Rq^T Rk : c = cq*ck+sq*sk, s = cq*sk-sq*ck (normalized)
    float inq0 = rsqrtf(r0.x * r0.x + r0.y * r0.y);
    float ink0 = rsqrtf(r1.x * r1.x + r1.y * r1.y);
    float cc0 = (r0.x * r1.x + r0.y * r1.y) * inq0 * ink0;
    float ss0 = (r0.x * r1.y - r0.y * r1.x) * inq0 * ink0;
    float y0 = cc0 * q.x - ss0 * q.y;
    float y1 = cc0 * q.y + ss0 * q.x;
    float inq1 = rsqrtf(r0.z * r0.z + r0.w * r0.w);
    float ink1 = rsqrtf(r1.z * r1.z + r1.w * r1.w);
    float cc1 = (r0.z * r1.z + r0.w * r1.w) * inq1 * ink1;
    float ss1 = (r0.z * r1.w - r0.w * r1.z) * inq1 * ink1;
    float y2 = cc1 * q.z - ss1 * q.w;
    float y3 = cc1 * q.w + ss1 * q.z;
    // v rotation (normalized)
    float inv0 = rsqrtf(r2.x * r2.x + r2.y * r2.y);
    float cv0 = r2.x * inv0, sv0 = r2.y * inv0;
    float v0 = cv0 * q.x - sv0 * q.y;
    float v1 = cv0 * q.y + sv0 * q.x;
    float inv1 = rsqrtf(r2.z * r2.z + r2.w * r2.w);
    float cv1 = r2.z * inv1, sv1 = r2.w * inv1;
    float v2 = cv1 * q.z - sv1 * q.w;
    float v3 = cv1 * q.w + sv1 * q.z;
    half4v kh = {(h16)y0, (h16)y1, (h16)y2, (h16)y3};
    half4v qh = {(h16)q.x, (h16)q.y, (h16)q.z, (h16)q.w};
    half4v vh = {(h16)v0, (h16)v1, (h16)v2, (h16)v3};
    *(half4v*)&Qhb[(size_t)row * D_ + col] = qh;
    *(half4v*)&Khb[(size_t)row * D_ + col] = kh;
    int pcol = col ^ ((row >> 3) << 3);  // XOR swizzle, keeps 8B alignment
    *(half4v*)&tile[row][pcol] = vh;
  }
  __syncthreads();
  h16* dst = VhT + ((size_t)b * D_ + d0) * S_ + s0;
#pragma unroll
  for (int i = 0; i < 2; ++i) {
    int c = t + 256 * i;   // 0..511 half8 chunks of the transposed tile
    int drow = c >> 3;     // d-local
    int sc = (c & 7) * 8;  // s-local, multiple of 8
    int xr = sc;           // (sc+j)>>3<<3 == sc for j<8
    half8 v;
#pragma unroll
    for (int j = 0; j < 8; ++j) v[j] = tile[sc + j][drow ^ xr];
    *(half8*)&dst[(size_t)drow * S_ + sc] = v;
  }
}

// ---------------- GEMM  C[m][n] = sum_k A[m][k] * Bt[n][k]  (fp16 in)
// Proven R5 structure: 128x128 tile, BK=64 as two BK=32 half-buffers (one
// barrier pair per 64-K), 4 waves each 64x64 (4x4 frags of 16x16x32),
// XOR-swizzled LDS chunks (measured 0 bank conflicts).
// NOTE (R4+R6): B must stay in LDS; register B-fragments from global collapse
// to MfmaUtil 13% (pre-barrier vmcnt(0) drain). Do not retry.
// XCD swizzle: consecutive linear block IDs round-robin across the 8 XCDs, so
// we remap ids so each XCD gets a compact m x n x batch rectangle (A+B fit its
// 4 MiB L2): GEMM1 4m x 8n (3 MB), GEMM2 4m x 4n (4 MB).
// OUT16: fp16 C (GEMM1 logits, grid 16x16x4) vs fp32 C (GEMM2, grid 8x16x4).
template <bool OUT16>
__global__ __launch_bounds__(256) void k_gemm_bt(
    const char* __restrict__ A, int a_pitch, unsigned long long a_batch,
    const char* __restrict__ Bt, int b_pitch, unsigned long long b_batch,
    void* __restrict__ C, int c_pitch, unsigned long long c_batch, int Kdim) {
  __shared__ __align__(16) h16 As[2][128 * 32];
  __shared__ __align__(16) h16 Bs[2][128 * 32];
  const int t = threadIdx.x;
  const int lane = t & 63;
  const int w = t >> 6;
  const int wm = (w >> 1) * 64;
  const int wn = (w & 1) * 64;

  // XCD-aware bijective remap (see header comment)
  const int id = blockIdx.x + gridDim.x * (blockIdx.y + 16 * blockIdx.z);
  const int xcd = id & 7;
  const int s = id >> 3;
  int tm, tn, tz;
  if constexpr (OUT16) {  // GEMM1: 16m x 16n x 4z, 128 ids/XCD
    tz = s >> 5;
    int tt = s & 31;
    tm = (xcd >> 1) * 4 + (tt >> 3);
    tn = (xcd & 1) * 8 + (tt & 7);
  } else {  // GEMM2: 16m x 8n x 4z, 64 ids/XCD
    tz = s >> 4;
    int tt = s & 15;
    tm = (xcd >> 1) * 4 + (tt >> 2);
    tn = (xcd & 1) * 4 + (tt & 3);
  }

  const char* Ab = A + (unsigned long long)tz * a_batch +
                   (unsigned long long)tm * 128ull * (unsigned long long)a_pitch;
  const char* Bbp = Bt + (unsigned long long)tz * b_batch +
                    (unsigned long long)tn * 128ull * (unsigned long long)b_pitch;
  const int o0 = t * 16;  // physical LDS byte offset (wave-uniform base + lane*16)
  const int o1 = o0 + 4096;
  const int ar0 = o0 >> 6, ar1 = o1 >> 6;
  const int ac0 = ((((o0 >> 4) & 3) ^ ((ar0 >> 1) & 3)) << 4);
  const int ac1 = ((((o1 >> 4) & 3) ^ ((ar1 >> 1) & 3)) << 4);
  const int mrow = lane & 15;
  const int kc = lane >> 4;                          // logical k-chunk 0..3
  const int koff = ((kc ^ ((mrow >> 1) & 3)) << 3);  // swizzled element offset

  floatx4 acc[4][4];
#pragma unroll
  for (int i = 0; i < 4; ++i)
#pragma unroll
    for (int j = 0; j < 4; ++j) acc[i][j] = (floatx4){0.f, 0.f, 0.f, 0.f};

  for (int kt = 0; kt < Kdim; kt += 64) {
    const int kb = kt * 2;  // byte col of this 64-K slab; halves at +0 / +64 B
#pragma unroll
    for (int h = 0; h < 2; ++h) {
      const int hb = kb + h * 64;
      gl_lds16(Ab + (unsigned long long)ar0 * a_pitch + hb + ac0, (char*)As[h] + o0);
      gl_lds16(Ab + (unsigned long long)ar1 * a_pitch + hb + ac1, (char*)As[h] + o1);
      gl_lds16(Bbp + (unsigned long long)ar0 * b_pitch + hb + ac0, (char*)Bs[h] + o0);
      gl_lds16(Bbp + (unsigned long long)ar1 * b_pitch + hb + ac1, (char*)Bs[h] + o1);
    }
    __syncthreads();
#pragma unroll
    for (int h = 0; h < 2; ++h) {
      half8 a[4], b[4];
#pragma unroll
      for (int i = 0; i < 4; ++i)
        a[i] = *(const half8*)&As[h][(wm + i * 16 + mrow) * 32 + koff];
#pragma unroll
      for (int i = 0; i < 4; ++i)
        b[i] = *(const half8*)&Bs[h][(wn + i * 16 + mrow) * 32 + koff];
#pragma unroll
      for (int i = 0; i < 4; ++i)
#pragma unroll
        for (int j = 0; j < 4; ++j)
          acc[i][j] = __builtin_amdgcn_mfma_f32_16x16x32_f16(a[i], b[j], acc[i][j], 0, 0, 0);
    }
    __syncthreads();
  }

  const int m0 = tm * 128 + wm;
  const int n0 = tn * 128 + wn;
  const int col = lane & 15;
  const int rquad = (lane >> 4) * 4;  // C/D: col=lane&15, row=(lane>>4)*4+reg
  if constexpr (OUT16) {
    h16* Cb = (h16*)C + (unsigned long long)tz * c_batch;
#pragma unroll
    for (int i = 0; i < 4; ++i)
#pragma unroll
      for (int j = 0; j < 4; ++j)
#pragma unroll
        for (int r = 0; r < 4; ++r)
          Cb[(unsigned long long)(m0 + i * 16 + rquad + r) * c_pitch + (n0 + j * 16 + col)] =
              (h16)acc[i][j][r];
  } else {
    float* Cb = (float*)C + (unsigned long long)tz * c_batch;
#pragma unroll
    for (int i = 0; i < 4; ++i)
#pragma unroll
      for (int j = 0; j < 4; ++j)
#pragma unroll
        for (int r = 0; r < 4; ++r)
          Cb[(unsigned long long)(m0 + i * 16 + rquad + r) * c_pitch + (n0 + j * 16 + col)] =
              acc[i][j][r];
  }
}

// ---- softmax: one WAVE per row (4 rows/block, no barriers), fp16 in place --
// Reads fp16 logits, writes unnormalized exp(l - rowmax) as fp16 at the same
// addresses. No sum needed: the softmax denominator cancels exactly in the
// final normalize (out = U/||U||). Safety: the cross-lane max reduction makes
// every store depend on every lane's loads.
__global__ __launch_bounds__(256) void k_softmax(h16* __restrict__ Sl,
                                                 const float* __restrict__ scale_p) {
  int wv = threadIdx.x >> 6, ln = threadIdx.x & 63;
  int row = blockIdx.x * 4 + wv;  // 0..B*S-1
  h16* base = Sl + (size_t)row * S_;
  half8 c[4];
#pragma unroll
  for (int r = 0; r < 4; ++r) c[r] = ((const half8*)base)[ln + 64 * r];
  float m = -1e30f;
#pragma unroll
  for (int r = 0; r < 4; ++r)
#pragma unroll
    for (int j = 0; j < 8; ++j) m = fmaxf(m, (float)c[r][j]);
#pragma unroll
  for (int off = 32; off; off >>= 1) m = fmaxf(m, __shfl_xor(m, off));
  float alpha = 2.0f / scale_p[0];  // +2, bias, 1/sum all cancel under normalize
#pragma unroll
  for (int r = 0; r < 4; ++r) {
    half8 pv;
#pragma unroll
    for (int j = 0; j < 8; ++j) pv[j] = (h16)__expf(((float)c[r][j] - m) * alpha);
    ((half8*)base)[ln + 64 * r] = pv;  // 16B/lane coalesced, in place
  }
}

// ---- epilogue: one WAVE per row (4 rows/block, no barriers) ----
// out = U/||U|| (Rv already folded into VhT; softmax denom cancels; reference
// clip can't trigger: ||ave|| >= ~0.02 >> 1e-4).
__global__ __launch_bounds__(256) void k_epilogue(float* __restrict__ O) {
  int wv = threadIdx.x >> 6, ln = threadIdx.x & 63;
  int row = blockIdx.x * 4 + wv;
  float* base = O + (size_t)row * D_;
  float4 u[4];
#pragma unroll
  for (int r = 0; r < 4; ++r) u[r] = ((const float4*)base)[ln + 64 * r];
  float ss = 0.f;
#pragma unroll
  for (int r = 0; r < 4; ++r)
    ss += u[r].x * u[r].x + u[r].y * u[r].y + u[r].z * u[r].z + u[r].w * u[r].w;
#pragma unroll
  for (int off = 32; off; off >>= 1) ss += __shfl_xor(ss, off);
  float f = rsqrtf(fmaxf(ss, 1e-30f));
#pragma unroll
  for (int r = 0; r < 4; ++r) {
    float4 o;
    o.x = u[r].x * f;
    o.y = u[r].y * f;
    o.z = u[r].z * f;
    o.w = u[r].w * f;
    ((float4*)base)[ln + 64 * r] = o;
  }
}

extern "C" void kernel_launch(void* const* d_in, const int* in_sizes, int n_in,
                              void* d_out, int out_size, void* d_ws, size_t ws_size,
                              hipStream_t stream) {
  const float* Q = (const float*)d_in[0];
  const float* rot = (const float*)d_in[1];
  const float* scale = (const float*)d_in[2];
  // bias (d_in[3]) is a scalar added to all logits -> cancels in softmax exactly.
  float* O = (float*)d_out;
  char* ws = (char*)d_ws;
  const size_t MB = 1024ull * 1024ull;
  h16* Qh = (h16*)(ws);             // 16 MB  [B][S][D]
  h16* Kh = (h16*)(ws + 16 * MB);   // 16 MB  [B][S][D]  combined-rotated
  h16* VhT = (h16*)(ws + 32 * MB);  // 16 MB  [B][D][S]  Rv-rotated, transposed
  h16* Sl = (h16*)(ws + 48 * MB);   // 32 MB  [B][S][S] fp16 logits, then P in place
  // total ws needed: 80 MB

  k_prep_t<<<dim3(D_ / 64, S_ / 64, Bb_), 256, 0, stream>>>(Q, rot, Qh, Kh, VhT);
  // GEMM1: logits[m][n] = Qh[m] . Kh[n]   (M=N=2048, K=1024), fp16 out
  k_gemm_bt<true><<<dim3(S_ / 128, S_ / 128, Bb_), 256, 0, stream>>>(
      (const char*)Qh, D_ * 2, (unsigned long long)S_ * D_ * 2,
      (const char*)Kh, D_ * 2, (unsigned long long)S_ * D_ * 2,
      (void*)Sl, S_, (unsigned long long)S_ * S_, D_);
  k_softmax<<<dim3(Bb_ * S_ / 4), 256, 0, stream>>>(Sl, scale);
  // GEMM2: U[m][d] = P[m] . VhT[d]        (M=2048, N=1024, K=2048), fp32 out
  k_gemm_bt<false><<<dim3(D_ / 128, S_ / 128, Bb_), 256, 0, stream>>>(
      (const char*)Sl, S_ * 2, (unsigned long long)S_ * S_ * 2,
      (const char*)VhT, S_ * 2, (unsigned long long)D_ * S_ * 2,
      (void*)O, D_, (unsigned long long)S_ * D_, S_);
  k_epilogue<<<dim3(Bb_ * S_ / 4), 256, 0, stream>>>(O);
}